// Round 1
// baseline (877.892 us; speedup 1.0000x reference)
//
#include <hip/hip_runtime.h>
#include <hip/hip_bf16.h>

#define NB   8
#define NPTS 8192
#define NT   2048
#define CWID 1024
#define DWID 256

using f32x4  = __attribute__((ext_vector_type(4))) float;
using bf16x8 = __attribute__((ext_vector_type(8))) __bf16;

// ---------------- ws layout (bytes) ----------------
#define OFF_INV    0u          // 8 f32 inv_p99
#define OFF_MASK   1024u       // 65536 u8
#define OFF_C      66560u      // 8x1024 f32
#define OFF_GB     99328u      // 22x8x256 f32 gamma/beta
#define OFF_STATS  279552u     // 256 mean + 256 rstd
#define OFF_SPART  281600u     // 128x512 f32 stat partials
#define OFF_W2T    1048576u    // 1024x1024 bf16 (W2 transposed)
#define OFF_H1     3145728u    // 8192x1024 bf16 (one batch)
#define OFF_NET    19922944u   // 16384x256 f32
#define OFF_DX     36700160u   // 16384x256 f32
#define WS_NEEDED  53477376u

__device__ __forceinline__ void async_copy16(const void* g, void* l) {
  __builtin_amdgcn_global_load_lds(
      (const __attribute__((address_space(1))) unsigned int*)g,
      (__attribute__((address_space(3))) unsigned int*)l, 16, 0, 0);
}

// ================= p99 selection + mask + zero(c) =================
__global__ __launch_bounds__(1024) void k_p99(
    const float* __restrict__ pts, float* __restrict__ inv_p99,
    unsigned char* __restrict__ mask, float* __restrict__ c)
{
  const int b = blockIdx.x;
  const int t = threadIdx.x;
  __shared__ unsigned int keys[NPTS];
  __shared__ int red[16];
  __shared__ int snv, stot;

  c[b*CWID + t] = 0.f;   // zero the pooled-feature buffer (1024 threads == CWID)

  int cnt = 0;
  for (int n = t; n < NPTS; n += 1024) {
    const float x = pts[(b*NPTS + n)*3 + 0];
    const float y = pts[(b*NPTS + n)*3 + 1];
    const float z = pts[(b*NPTS + n)*3 + 2];
    const bool v = x > -50.f;
    mask[b*NPTS + n] = v ? 1 : 0;
    unsigned int key = 0x7F800000u;  // +inf
    if (v) { key = __float_as_uint(sqrtf(x*x + y*y + z*z)); cnt++; }
    keys[n] = key;
  }
  #pragma unroll
  for (int o = 32; o > 0; o >>= 1) cnt += __shfl_down(cnt, o);
  if ((t & 63) == 0) red[t >> 6] = cnt;
  __syncthreads();
  if (t == 0) { int s = 0; for (int i = 0; i < 16; ++i) s += red[i]; snv = s; }
  __syncthreads();
  const int nv = snv;
  const int kk = 1 + (int)rintf(0.99f * (float)(nv - 1));

  unsigned int lo = 0, hi = 0x7F800000u;
  while (lo < hi) {
    const unsigned int mid = lo + ((hi - lo) >> 1);
    int cl = 0;
    for (int n = t; n < NPTS; n += 1024) cl += (keys[n] <= mid) ? 1 : 0;
    #pragma unroll
    for (int o = 32; o > 0; o >>= 1) cl += __shfl_down(cl, o);
    if ((t & 63) == 0) red[t >> 6] = cl;
    __syncthreads();
    if (t == 0) { int s = 0; for (int i = 0; i < 16; ++i) s += red[i]; stot = s; }
    __syncthreads();
    if (stot >= kk) hi = mid; else lo = mid + 1;
  }
  if (t == 0) inv_p99[b] = 1.0f / __uint_as_float(lo);
}

// ================= W2 -> W2^T bf16 =================
__global__ __launch_bounds__(256) void k_w2t(
    const float* __restrict__ w2, __hip_bfloat16* __restrict__ w2t)
{
  __shared__ float tile[64][65];
  const int kb = blockIdx.x * 64, nb = blockIdx.y * 64;
  const int t = threadIdx.x;
  const int cc = t & 63, rq = t >> 6;
  #pragma unroll
  for (int i = 0; i < 16; ++i) {
    const int r = i*4 + rq;
    tile[r][cc] = w2[(kb + r)*CWID + nb + cc];
  }
  __syncthreads();
  #pragma unroll
  for (int i = 0; i < 16; ++i) {
    const int r = i*4 + rq;
    w2t[(size_t)(nb + r)*CWID + kb + cc] = __float2bfloat16(tile[cc][r]);
  }
}

// ================= encoder layer 1 (one batch) -> h1 bf16 =================
__global__ __launch_bounds__(256) void k_enc1(
    const float* __restrict__ pts, const float* __restrict__ rgb,
    const float* __restrict__ inv_p99,
    const float* __restrict__ W1, const float* __restrict__ b1,
    __hip_bfloat16* __restrict__ h1, int b)
{
  __shared__ float xs[8][6];
  const int r0 = blockIdx.x * 8;
  const int t = threadIdx.x;
  if (t < 48) {
    const int m = t / 6, j = t % 6;
    const int gi = b*NPTS + r0 + m;
    const float inv = inv_p99[b];
    xs[m][j] = (j < 3) ? pts[gi*3 + j] * inv : rgb[gi*3 + j - 3];
  }
  __syncthreads();
  for (int col = t; col < CWID; col += 256) {
    const float w0 = W1[col],        w1 = W1[CWID + col],   w2 = W1[2*CWID + col];
    const float w3 = W1[3*CWID+col], w4 = W1[4*CWID + col], w5 = W1[5*CWID + col];
    const float bb = b1[col];
    #pragma unroll
    for (int m = 0; m < 8; ++m) {
      const float a = bb + xs[m][0]*w0 + xs[m][1]*w1 + xs[m][2]*w2
                         + xs[m][3]*w3 + xs[m][4]*w4 + xs[m][5]*w5;
      h1[(size_t)(r0 + m)*CWID + col] = __float2bfloat16(fmaxf(a, 0.f));
    }
  }
}

// ================= encoder layer 2 (MFMA) + masked max-pool =================
#define EBM 128
#define EBN 128
#define EBK 64

__device__ __forceinline__ void enc2_stage(
    const __hip_bfloat16* __restrict__ ga, const __hip_bfloat16* __restrict__ gb,
    __hip_bfloat16* As, __hip_bfloat16* Bs,
    int m0, int n0, int k0, int wid, int lane)
{
  #pragma unroll
  for (int q = 0; q < 4; ++q) {
    const int cib = q*256 + wid*64;    // wave-uniform chunk base
    const int ci  = cib + lane;
    async_copy16(ga + (size_t)(m0 + (ci >> 3))*CWID + k0 + (ci & 7)*8, As + cib*8);
    async_copy16(gb + (size_t)(n0 + (ci >> 3))*CWID + k0 + (ci & 7)*8, Bs + cib*8);
  }
}

__global__ __launch_bounds__(256) void k_enc2(
    const __hip_bfloat16* __restrict__ h1,   // [8192][1024] one batch
    const __hip_bfloat16* __restrict__ w2t,  // [1024][1024] n-major
    const float* __restrict__ b2,
    const unsigned char* __restrict__ mask_b, // + b*8192
    float* __restrict__ c_b)                  // + b*1024
{
  __shared__ __align__(16) __hip_bfloat16 As[2][EBM*EBK];
  __shared__ __align__(16) __hip_bfloat16 Bs[2][EBN*EBK];
  const int tid = threadIdx.x;
  const int lane = tid & 63, wid = tid >> 6;
  const int wm = wid >> 1, wn = wid & 1;
  const int m0 = blockIdx.x * EBM;
  const int n0 = blockIdx.y * EBN;

  f32x4 acc[4][4] = {};

  enc2_stage(h1, w2t, As[0], Bs[0], m0, n0, 0, wid, lane);
  for (int kt = 0; kt < 16; ++kt) {
    const int cur = kt & 1;
    __syncthreads();  // drains this wave's global_load_lds (vmcnt) + barrier
    if (kt < 15) enc2_stage(h1, w2t, As[cur^1], Bs[cur^1], m0, n0, (kt+1)*EBK, wid, lane);
    #pragma unroll
    for (int ks = 0; ks < 2; ++ks) {
      const int ke = ks*32 + (lane >> 4)*8;
      bf16x8 a[4], bfr[4];
      #pragma unroll
      for (int f = 0; f < 4; ++f) {
        a[f]   = *reinterpret_cast<const bf16x8*>(&As[cur][(wm*64 + f*16 + (lane & 15))*EBK + ke]);
        bfr[f] = *reinterpret_cast<const bf16x8*>(&Bs[cur][(wn*64 + f*16 + (lane & 15))*EBK + ke]);
      }
      #pragma unroll
      for (int fm = 0; fm < 4; ++fm)
        #pragma unroll
        for (int fn = 0; fn < 4; ++fn)
          acc[fm][fn] = __builtin_amdgcn_mfma_f32_16x16x32_bf16(a[fm], bfr[fn], acc[fm][fn], 0, 0, 0);
    }
  }

  // epilogue: bias + relu + masked max over rows -> atomicMax into c
  const int rbase = (lane >> 4)*4;
  #pragma unroll
  for (int fn = 0; fn < 4; ++fn) {
    const int gn = n0 + wn*64 + fn*16 + (lane & 15);
    const float bv = b2[gn];
    float mx = 0.f;
    #pragma unroll
    for (int fm = 0; fm < 4; ++fm) {
      const int gmb = m0 + wm*64 + fm*16 + rbase;
      #pragma unroll
      for (int r = 0; r < 4; ++r) {
        const float v = fmaxf(acc[fm][fn][r] + bv, 0.f);
        if (mask_b[gmb + r]) mx = fmaxf(mx, v);
      }
    }
    mx = fmaxf(mx, __shfl_xor(mx, 16));
    mx = fmaxf(mx, __shfl_xor(mx, 32));
    if ((lane >> 4) == 0)
      atomicMax((int*)(c_b + gn), __float_as_int(mx));  // values >= 0: int order == float order
  }
}

// ================= gamma/beta for all 22 CBN slots =================
__global__ __launch_bounds__(256) void k_gb(
    const float* __restrict__ c,
    const float* __restrict__ Wg0, const float* __restrict__ bg0,
    const float* __restrict__ Wb0, const float* __restrict__ bb0,
    const float* __restrict__ Wg1, const float* __restrict__ bg1,
    const float* __restrict__ Wb1, const float* __restrict__ bb1,
    const float* __restrict__ bnWg, const float* __restrict__ bnbg,
    const float* __restrict__ bnWb, const float* __restrict__ bnbb,
    float* __restrict__ gb)
{
  const int s = blockIdx.y;   // slot 0..21
  const int q = blockIdx.x;   // col quarter
  const int t = threadIdx.x;
  const int col = q*64 + (t & 63);
  const int bp = t >> 6;      // batches 2bp, 2bp+1
  const float* W; const float* bias;
  if      (s < 5)  { W = Wg0 + (size_t)s*CWID*DWID;      bias = bg0 + s*DWID; }
  else if (s < 10) { W = Wb0 + (size_t)(s-5)*CWID*DWID;  bias = bb0 + (s-5)*DWID; }
  else if (s < 15) { W = Wg1 + (size_t)(s-10)*CWID*DWID; bias = bg1 + (s-10)*DWID; }
  else if (s < 20) { W = Wb1 + (size_t)(s-15)*CWID*DWID; bias = bb1 + (s-15)*DWID; }
  else if (s == 20){ W = bnWg; bias = bnbg; }
  else             { W = bnWb; bias = bnbb; }
  float a0 = 0.f, a1 = 0.f;
  for (int k = 0; k < CWID; ++k) {
    const float w = W[(size_t)k*DWID + col];
    a0 += c[(2*bp)  *CWID + k] * w;
    a1 += c[(2*bp+1)*CWID + k] * w;
  }
  gb[((size_t)s*8 + 2*bp)  *DWID + col] = a0 + bias[col];
  gb[((size_t)s*8 + 2*bp+1)*DWID + col] = a1 + bias[col];
}

// ================= fc_p: net = (query/p99) @ W + b =================
__global__ __launch_bounds__(256) void k_fcp(
    const float* __restrict__ qc, const float* __restrict__ inv_p99,
    const float* __restrict__ W, const float* __restrict__ bias,
    float* __restrict__ net)
{
  const int m = blockIdx.x;
  const int n = threadIdx.x;
  const int b = m >> 11;
  const float inv = inv_p99[b];
  const float q0 = qc[m*3+0]*inv, q1 = qc[m*3+1]*inv, q2 = qc[m*3+2]*inv;
  net[(size_t)m*DWID + n] = bias[n] + q0*W[n] + q1*W[DWID + n] + q2*W[2*DWID + n];
}

// ================= batch-stat partials / final =================
__global__ __launch_bounds__(256) void k_statp(
    const float* __restrict__ X, float* __restrict__ part)
{
  const int r0 = blockIdx.x * 128;
  const int f = threadIdx.x;
  float s = 0.f, q = 0.f;
  for (int m = 0; m < 128; ++m) {
    const float v = X[(size_t)(r0 + m)*DWID + f];
    s += v; q += v*v;
  }
  part[blockIdx.x*512 + f] = s;
  part[blockIdx.x*512 + 256 + f] = q;
}

__global__ __launch_bounds__(256) void k_statf(
    const float* __restrict__ part, float* __restrict__ stats)
{
  const int f = threadIdx.x;
  float s = 0.f, q = 0.f;
  for (int i = 0; i < 128; ++i) { s += part[i*512 + f]; q += part[i*512 + 256 + f]; }
  const float mean = s * (1.f/16384.f);
  const float var  = q * (1.f/16384.f) - mean*mean;
  stats[f] = mean;
  stats[256 + f] = rsqrtf(var + 1e-5f);
}

// ================= CBN + relu + matmul (+optional residual add) =================
__global__ __launch_bounds__(256) void k_cbnmm(
    const float* __restrict__ X, const float* __restrict__ stats,
    const float* __restrict__ gb, int gslot, int bslot,
    const float* __restrict__ W, const float* __restrict__ bias,
    float* __restrict__ out, int addmode)
{
  __shared__ float xs[32][256];
  const int r0 = blockIdx.x * 32;
  const int bb = r0 >> 11;
  const int t = threadIdx.x;
  {
    const float mn = stats[t];
    const float rs = stats[256 + t];
    const float g  = gb[((size_t)gslot*8 + bb)*DWID + t];
    const float be = gb[((size_t)bslot*8 + bb)*DWID + t];
    for (int m = 0; m < 32; ++m) {
      const float v = X[(size_t)(r0 + m)*DWID + t];
      xs[m][t] = fmaxf(0.f, (v - mn)*rs*g + be);
    }
  }
  __syncthreads();
  const int c0 = (t & 63) * 4;
  const int rq = t >> 6;
  f32x4 acc[8] = {};
  for (int k4 = 0; k4 < 64; ++k4) {
    f32x4 w[4];
    #pragma unroll
    for (int j = 0; j < 4; ++j)
      w[j] = *reinterpret_cast<const f32x4*>(&W[(size_t)(k4*4 + j)*DWID + c0]);
    #pragma unroll
    for (int m = 0; m < 8; ++m) {
      const f32x4 xv = *reinterpret_cast<const f32x4*>(&xs[rq*8 + m][k4*4]);
      f32x4 a = acc[m];
      a = a + w[0]*xv[0];
      a = a + w[1]*xv[1];
      a = a + w[2]*xv[2];
      a = a + w[3]*xv[3];
      acc[m] = a;
    }
  }
  const f32x4 bs = *reinterpret_cast<const f32x4*>(&bias[c0]);
  #pragma unroll
  for (int m = 0; m < 8; ++m) {
    const size_t row = (size_t)(r0 + rq*8 + m);
    f32x4 v = acc[m] + bs;
    if (addmode) v = v + *reinterpret_cast<const f32x4*>(&out[row*DWID + c0]);
    *reinterpret_cast<f32x4*>(&out[row*DWID + c0]) = v;
  }
}

// ================= final CBN + relu + fc_out =================
__global__ __launch_bounds__(256) void k_final(
    const float* __restrict__ net, const float* __restrict__ stats,
    const float* __restrict__ gb, const float* __restrict__ fcW,
    const float* __restrict__ fcb, float* __restrict__ out)
{
  const int wid = threadIdx.x >> 6, lane = threadIdx.x & 63;
  const int m = blockIdx.x*4 + wid;
  const int b = m >> 11;
  const int f0 = lane*4;
  const f32x4 x  = *reinterpret_cast<const f32x4*>(&net[(size_t)m*DWID + f0]);
  const f32x4 mn = *reinterpret_cast<const f32x4*>(&stats[f0]);
  const f32x4 rs = *reinterpret_cast<const f32x4*>(&stats[256 + f0]);
  const f32x4 g  = *reinterpret_cast<const f32x4*>(&gb[(20*8 + (size_t)b)*DWID + f0]);
  const f32x4 be = *reinterpret_cast<const f32x4*>(&gb[(21*8 + (size_t)b)*DWID + f0]);
  const f32x4 w  = *reinterpret_cast<const f32x4*>(&fcW[f0]);
  float s = 0.f;
  #pragma unroll
  for (int j = 0; j < 4; ++j)
    s += fmaxf(0.f, (x[j] - mn[j])*rs[j]*g[j] + be[j]) * w[j];
  #pragma unroll
  for (int o = 32; o > 0; o >>= 1) s += __shfl_down(s, o);
  if (lane == 0) out[m] = s + fcb[0];
}

// ================= launch =================
extern "C" void kernel_launch(void* const* d_in, const int* in_sizes, int n_in,
                              void* d_out, int out_size, void* d_ws, size_t ws_size,
                              hipStream_t stream) {
  (void)in_sizes; (void)n_in; (void)out_size;
  if (ws_size < WS_NEEDED) return;

  const float* pts    = (const float*)d_in[0];
  const float* rgb    = (const float*)d_in[1];
  const float* qc     = (const float*)d_in[2];
  const float* enc_W1 = (const float*)d_in[3];
  const float* enc_b1 = (const float*)d_in[4];
  const float* enc_W2 = (const float*)d_in[5];
  const float* enc_b2 = (const float*)d_in[6];
  const float* fc_p_W = (const float*)d_in[7];
  const float* fc_p_b = (const float*)d_in[8];
  const float* Wg0 = (const float*)d_in[9];
  const float* bg0 = (const float*)d_in[10];
  const float* Wb0 = (const float*)d_in[11];
  const float* bb0 = (const float*)d_in[12];
  const float* W0  = (const float*)d_in[13];
  const float* b0  = (const float*)d_in[14];
  const float* Wg1 = (const float*)d_in[15];
  const float* bg1 = (const float*)d_in[16];
  const float* Wb1 = (const float*)d_in[17];
  const float* bb1 = (const float*)d_in[18];
  const float* W1  = (const float*)d_in[19];
  const float* b1  = (const float*)d_in[20];
  const float* bnWg = (const float*)d_in[21];
  const float* bnbg = (const float*)d_in[22];
  const float* bnWb = (const float*)d_in[23];
  const float* bnbb = (const float*)d_in[24];
  const float* fcoW = (const float*)d_in[25];
  const float* fcob = (const float*)d_in[26];
  float* out = (float*)d_out;

  char* ws = (char*)d_ws;
  float* inv_p99 = (float*)(ws + OFF_INV);
  unsigned char* mask = (unsigned char*)(ws + OFF_MASK);
  float* c     = (float*)(ws + OFF_C);
  float* gbuf  = (float*)(ws + OFF_GB);
  float* stats = (float*)(ws + OFF_STATS);
  float* part  = (float*)(ws + OFF_SPART);
  __hip_bfloat16* w2t = (__hip_bfloat16*)(ws + OFF_W2T);
  __hip_bfloat16* h1  = (__hip_bfloat16*)(ws + OFF_H1);
  float* net = (float*)(ws + OFF_NET);
  float* dx  = (float*)(ws + OFF_DX);

  k_p99<<<NB, 1024, 0, stream>>>(pts, inv_p99, mask, c);
  k_w2t<<<dim3(16,16), 256, 0, stream>>>(enc_W2, w2t);
  for (int b = 0; b < NB; ++b) {
    k_enc1<<<NPTS/8, 256, 0, stream>>>(pts, rgb, inv_p99, enc_W1, enc_b1, h1, b);
    k_enc2<<<dim3(NPTS/EBM, CWID/EBN), 256, 0, stream>>>(h1, w2t, enc_b2,
                                                         mask + b*NPTS, c + b*CWID);
  }
  k_gb<<<dim3(4,22), 256, 0, stream>>>(c, Wg0,bg0, Wb0,bb0, Wg1,bg1, Wb1,bb1,
                                       bnWg,bnbg, bnWb,bnbb, gbuf);
  k_fcp<<<NB*NT, 256, 0, stream>>>(qc, inv_p99, fc_p_W, fc_p_b, net);

  for (int i = 0; i < 5; ++i) {
    k_statp<<<128, 256, 0, stream>>>(net, part);
    k_statf<<<1, 256, 0, stream>>>(part, stats);
    k_cbnmm<<<512, 256, 0, stream>>>(net, stats, gbuf, i, 5+i,
                                     W0 + (size_t)i*DWID*DWID, b0 + i*DWID, dx, 0);
    k_statp<<<128, 256, 0, stream>>>(dx, part);
    k_statf<<<1, 256, 0, stream>>>(part, stats);
    k_cbnmm<<<512, 256, 0, stream>>>(dx, stats, gbuf, 10+i, 15+i,
                                     W1 + (size_t)i*DWID*DWID, b1 + i*DWID, net, 1);
  }
  k_statp<<<128, 256, 0, stream>>>(net, part);
  k_statf<<<1, 256, 0, stream>>>(part, stats);
  k_final<<<NB*NT/4, 256, 0, stream>>>(net, stats, gbuf, fcoW, fcob, out);
}

// Round 3
// 801.837 us; speedup vs baseline: 1.0949x; 1.0949x over previous
//
#include <hip/hip_runtime.h>
#include <hip/hip_bf16.h>

#define NB   8
#define NPTS 8192
#define NT   2048
#define CWID 1024
#define DWID 256

using f32x4  = __attribute__((ext_vector_type(4))) float;
using bf16x8 = __attribute__((ext_vector_type(8))) __bf16;
using bf16x4 = __attribute__((ext_vector_type(4))) __bf16;

// ---------------- ws layout (bytes) ----------------
#define OFF_INV    0u          // 8 f32 inv_p99
#define OFF_MASK   1024u       // 65536 u8
#define OFF_C      66560u      // 8x1024 f32
#define OFF_GB     99328u      // 22x8x256 f32 gamma/beta
#define OFF_STATS  279552u     // 256 mean + 256 rstd
#define OFF_W2T    1048576u    // 1024x1024 bf16 (W2 transposed)
#define OFF_H1     3145728u    // 8192x1024 bf16 (one batch) -- dead after encoder
#define OFF_WT     3145728u    // aliases h1: 10x256x256 bf16 (decoder W, n-major)
#define OFF_GBP    4456448u    // aliases h1: 22x16x8x256 f32 gb partials
#define OFF_PART   7340032u    // aliases h1: 256x512 f32 stat partials
#define OFF_NET    19922944u   // 16384x256 f32
#define OFF_DX     36700160u   // 16384x256 f32
#define WS_NEEDED  53477376u

__device__ __forceinline__ void async_copy16(const void* g, void* l) {
  __builtin_amdgcn_global_load_lds(
      (const __attribute__((address_space(1))) unsigned int*)g,
      (__attribute__((address_space(3))) unsigned int*)l, 16, 0, 0);
}

// ================= p99 (4-pass radix select) + mask + zero(c) =================
__global__ __launch_bounds__(1024) void k_p99(
    const float* __restrict__ pts, float* __restrict__ inv_p99,
    unsigned char* __restrict__ mask, float* __restrict__ c)
{
  const int b = blockIdx.x;
  const int t = threadIdx.x;
  __shared__ unsigned int keys[NPTS];
  __shared__ int whist[16][256];
  __shared__ int hist[256];
  __shared__ int red[16];
  __shared__ int s_nv, s_kleft;
  __shared__ unsigned int s_prefix;

  c[b*CWID + t] = 0.f;   // zero pooled-feature buffer (1024 threads == CWID)

  int cnt = 0;
  for (int n = t; n < NPTS; n += 1024) {
    const float x = pts[(b*NPTS + n)*3 + 0];
    const float y = pts[(b*NPTS + n)*3 + 1];
    const float z = pts[(b*NPTS + n)*3 + 2];
    const bool v = x > -50.f;
    mask[b*NPTS + n] = v ? 1 : 0;
    unsigned int key = 0x7F800000u;  // +inf
    if (v) { key = __float_as_uint(sqrtf(x*x + y*y + z*z)); cnt++; }
    keys[n] = key;
  }
  #pragma unroll
  for (int o = 32; o > 0; o >>= 1) cnt += __shfl_down(cnt, o);
  if ((t & 63) == 0) red[t >> 6] = cnt;
  __syncthreads();
  if (t == 0) {
    int s = 0; for (int i = 0; i < 16; ++i) s += red[i];
    s_nv = s;
    s_kleft = 1 + (int)rintf(0.99f * (float)(s - 1));
    s_prefix = 0u;
  }
  __syncthreads();

  const int w = t >> 6;
  for (int pass = 0; pass < 4; ++pass) {
    const int shift = 24 - 8*pass;
    const unsigned int pref = s_prefix;
    for (int i = t; i < 16*256; i += 1024) ((int*)whist)[i] = 0;
    __syncthreads();
    for (int n = t; n < NPTS; n += 1024) {
      const unsigned int key = keys[n];
      const bool m = (pass == 0) || ((key >> (shift + 8)) == (pref >> (shift + 8)));
      if (m) atomicAdd(&whist[w][(key >> shift) & 255], 1);
    }
    __syncthreads();
    if (t < 256) { int h = 0; for (int ww = 0; ww < 16; ++ww) h += whist[ww][t]; hist[t] = h; }
    __syncthreads();
    if (t == 0) {
      int cum = 0; const int kl = s_kleft; unsigned int bin = 0;
      for (int bn = 0; bn < 256; ++bn) {
        const int cc = hist[bn];
        if (cum + cc >= kl) { bin = (unsigned int)bn; break; }
        cum += cc;
      }
      s_prefix = pref | (bin << shift);
      s_kleft = kl - cum;
    }
    __syncthreads();
  }
  if (t == 0) inv_p99[b] = 1.0f / __uint_as_float(s_prefix);
}

// ================= W2 -> W2^T bf16 =================
__global__ __launch_bounds__(256) void k_w2t(
    const float* __restrict__ w2, __hip_bfloat16* __restrict__ w2t)
{
  __shared__ float tile[64][65];
  const int kb = blockIdx.x * 64, nb = blockIdx.y * 64;
  const int t = threadIdx.x;
  const int cc = t & 63, rq = t >> 6;
  #pragma unroll
  for (int i = 0; i < 16; ++i) {
    const int r = i*4 + rq;
    tile[r][cc] = w2[(kb + r)*CWID + nb + cc];
  }
  __syncthreads();
  #pragma unroll
  for (int i = 0; i < 16; ++i) {
    const int r = i*4 + rq;
    w2t[(size_t)(nb + r)*CWID + kb + cc] = __float2bfloat16(tile[cc][r]);
  }
}

// ================= decoder W0/W1 -> wt bf16 (n-major) =================
__global__ __launch_bounds__(256) void k_wt(
    const float* __restrict__ W0, const float* __restrict__ W1,
    __hip_bfloat16* __restrict__ wt)
{
  __shared__ float tile[64][65];
  const int s = blockIdx.z;
  const float* src = (s < 5) ? (W0 + (size_t)s*DWID*DWID) : (W1 + (size_t)(s-5)*DWID*DWID);
  const int kb = blockIdx.x * 64, nb = blockIdx.y * 64;
  const int t = threadIdx.x;
  const int cc = t & 63, rq = t >> 6;
  #pragma unroll
  for (int i = 0; i < 16; ++i) {
    const int r = i*4 + rq;
    tile[r][cc] = src[(kb + r)*DWID + nb + cc];
  }
  __syncthreads();
  #pragma unroll
  for (int i = 0; i < 16; ++i) {
    const int r = i*4 + rq;
    wt[(size_t)s*DWID*DWID + (size_t)(nb + r)*DWID + kb + cc] = __float2bfloat16(tile[cc][r]);
  }
}

// ================= encoder layer 1 (one batch) -> h1 bf16 =================
__global__ __launch_bounds__(256) void k_enc1(
    const float* __restrict__ pts, const float* __restrict__ rgb,
    const float* __restrict__ inv_p99,
    const float* __restrict__ W1, const float* __restrict__ b1,
    __hip_bfloat16* __restrict__ h1, int b)
{
  __shared__ float xs[8][6];
  const int r0 = blockIdx.x * 8;
  const int t = threadIdx.x;
  if (t < 48) {
    const int m = t / 6, j = t % 6;
    const int gi = b*NPTS + r0 + m;
    const float inv = inv_p99[b];
    xs[m][j] = (j < 3) ? pts[gi*3 + j] * inv : rgb[gi*3 + j - 3];
  }
  __syncthreads();
  for (int col = t; col < CWID; col += 256) {
    const float w0 = W1[col],        w1 = W1[CWID + col],   w2 = W1[2*CWID + col];
    const float w3 = W1[3*CWID+col], w4 = W1[4*CWID + col], w5 = W1[5*CWID + col];
    const float bb = b1[col];
    #pragma unroll
    for (int m = 0; m < 8; ++m) {
      const float a = bb + xs[m][0]*w0 + xs[m][1]*w1 + xs[m][2]*w2
                         + xs[m][3]*w3 + xs[m][4]*w4 + xs[m][5]*w5;
      h1[(size_t)(r0 + m)*CWID + col] = __float2bfloat16(fmaxf(a, 0.f));
    }
  }
}

// ================= encoder layer 2 (MFMA) + masked max-pool =================
#define EBM 128
#define EBN 128
#define EBK 64

__device__ __forceinline__ void enc2_stage(
    const __hip_bfloat16* __restrict__ ga, const __hip_bfloat16* __restrict__ gb,
    __hip_bfloat16* As, __hip_bfloat16* Bs,
    int m0, int n0, int k0, int wid, int lane)
{
  #pragma unroll
  for (int q = 0; q < 4; ++q) {
    const int cib = q*256 + wid*64;    // wave-uniform chunk base
    const int ci  = cib + lane;
    async_copy16(ga + (size_t)(m0 + (ci >> 3))*CWID + k0 + (ci & 7)*8, As + cib*8);
    async_copy16(gb + (size_t)(n0 + (ci >> 3))*CWID + k0 + (ci & 7)*8, Bs + cib*8);
  }
}

__global__ __launch_bounds__(256) void k_enc2(
    const __hip_bfloat16* __restrict__ h1,   // [8192][1024] one batch
    const __hip_bfloat16* __restrict__ w2t,  // [1024][1024] n-major
    const float* __restrict__ b2,
    const unsigned char* __restrict__ mask_b, // + b*8192
    float* __restrict__ c_b)                  // + b*1024
{
  __shared__ __align__(16) __hip_bfloat16 As[2][EBM*EBK];
  __shared__ __align__(16) __hip_bfloat16 Bs[2][EBN*EBK];
  const int tid = threadIdx.x;
  const int lane = tid & 63, wid = tid >> 6;
  const int wm = wid >> 1, wn = wid & 1;
  const int m0 = blockIdx.x * EBM;
  const int n0 = blockIdx.y * EBN;

  f32x4 acc[4][4] = {};

  enc2_stage(h1, w2t, As[0], Bs[0], m0, n0, 0, wid, lane);
  for (int kt = 0; kt < 16; ++kt) {
    const int cur = kt & 1;
    __syncthreads();
    if (kt < 15) enc2_stage(h1, w2t, As[cur^1], Bs[cur^1], m0, n0, (kt+1)*EBK, wid, lane);
    #pragma unroll
    for (int ks = 0; ks < 2; ++ks) {
      const int ke = ks*32 + (lane >> 4)*8;
      bf16x8 a[4], bfr[4];
      #pragma unroll
      for (int f = 0; f < 4; ++f) {
        a[f]   = *reinterpret_cast<const bf16x8*>(&As[cur][(wm*64 + f*16 + (lane & 15))*EBK + ke]);
        bfr[f] = *reinterpret_cast<const bf16x8*>(&Bs[cur][(wn*64 + f*16 + (lane & 15))*EBK + ke]);
      }
      #pragma unroll
      for (int fm = 0; fm < 4; ++fm)
        #pragma unroll
        for (int fn = 0; fn < 4; ++fn)
          acc[fm][fn] = __builtin_amdgcn_mfma_f32_16x16x32_bf16(a[fm], bfr[fn], acc[fm][fn], 0, 0, 0);
    }
  }

  const int rbase = (lane >> 4)*4;
  #pragma unroll
  for (int fn = 0; fn < 4; ++fn) {
    const int gn = n0 + wn*64 + fn*16 + (lane & 15);
    const float bv = b2[gn];
    float mx = 0.f;
    #pragma unroll
    for (int fm = 0; fm < 4; ++fm) {
      const int gmb = m0 + wm*64 + fm*16 + rbase;
      #pragma unroll
      for (int r = 0; r < 4; ++r) {
        const float v = fmaxf(acc[fm][fn][r] + bv, 0.f);
        if (mask_b[gmb + r]) mx = fmaxf(mx, v);
      }
    }
    mx = fmaxf(mx, __shfl_xor(mx, 16));
    mx = fmaxf(mx, __shfl_xor(mx, 32));
    if ((lane >> 4) == 0)
      atomicMax((int*)(c_b + gn), __float_as_int(mx));  // values >= 0
  }
}

// ================= gamma/beta: stage A (split-K partials) =================
__global__ __launch_bounds__(256) void k_gbp(
    const float* __restrict__ c,
    const float* __restrict__ Wg0, const float* __restrict__ Wb0,
    const float* __restrict__ Wg1, const float* __restrict__ Wb1,
    const float* __restrict__ bnWg, const float* __restrict__ bnWb,
    float* __restrict__ gbp)
{
  __shared__ float cs[8][64];
  __shared__ float red[4][8][256];
  const int s  = blockIdx.y;
  const int kc = blockIdx.x;
  const int k0 = kc * 64;
  const int t  = threadIdx.x;

  const float* W;
  if      (s < 5)  W = Wg0 + (size_t)s*CWID*DWID;
  else if (s < 10) W = Wb0 + (size_t)(s-5)*CWID*DWID;
  else if (s < 15) W = Wg1 + (size_t)(s-10)*CWID*DWID;
  else if (s < 20) W = Wb1 + (size_t)(s-15)*CWID*DWID;
  else if (s == 20) W = bnWg;
  else              W = bnWb;

  {
    const int i0 = t*2;
    cs[i0 >> 6][i0 & 63]       = c[(i0 >> 6)*CWID + k0 + (i0 & 63)];
    cs[(i0+1) >> 6][(i0+1) & 63] = c[((i0+1) >> 6)*CWID + k0 + ((i0+1) & 63)];
  }
  __syncthreads();

  const int sub = t >> 6;
  const int c0  = (t & 63) * 4;
  f32x4 acc[8] = {};
  #pragma unroll
  for (int i = 0; i < 16; ++i) {
    const int kk = sub*16 + i;
    const f32x4 w = *reinterpret_cast<const f32x4*>(&W[(size_t)(k0 + kk)*DWID + c0]);
    #pragma unroll
    for (int b = 0; b < 8; ++b) acc[b] = acc[b] + w * cs[b][kk];
  }
  #pragma unroll
  for (int b = 0; b < 8; ++b)
    *reinterpret_cast<f32x4*>(&red[sub][b][c0]) = acc[b];
  __syncthreads();
  for (int b = 0; b < 8; ++b) {
    const float v = red[0][b][t] + red[1][b][t] + red[2][b][t] + red[3][b][t];
    gbp[(((size_t)s*16 + kc)*8 + b)*DWID + t] = v;
  }
}

// ================= gamma/beta: stage B (reduce + bias) =================
__global__ __launch_bounds__(256) void k_gbf(
    const float* __restrict__ gbp,
    const float* __restrict__ bg0, const float* __restrict__ bb0,
    const float* __restrict__ bg1, const float* __restrict__ bb1,
    const float* __restrict__ bnbg, const float* __restrict__ bnbb,
    float* __restrict__ gb)
{
  const int s = blockIdx.x;
  const int t = threadIdx.x;
  const float* bias;
  if      (s < 5)  bias = bg0 + s*DWID;
  else if (s < 10) bias = bb0 + (s-5)*DWID;
  else if (s < 15) bias = bg1 + (s-10)*DWID;
  else if (s < 20) bias = bb1 + (s-15)*DWID;
  else if (s == 20) bias = bnbg;
  else              bias = bnbb;
  const float bv = bias[t];
  for (int b = 0; b < 8; ++b) {
    float acc = bv;
    #pragma unroll
    for (int kc = 0; kc < 16; ++kc)
      acc += gbp[(((size_t)s*16 + kc)*8 + b)*DWID + t];
    gb[((size_t)s*8 + b)*DWID + t] = acc;
  }
}

// ================= fc_p (64 rows/block) + fused stat partials =================
__global__ __launch_bounds__(256) void k_fcp2(
    const float* __restrict__ qc, const float* __restrict__ inv_p99,
    const float* __restrict__ W, const float* __restrict__ bias,
    float* __restrict__ net, float* __restrict__ part)
{
  __shared__ float qs[192];
  const int blk = blockIdx.x;
  const int r0 = blk * 64;
  const int b = r0 >> 11;
  const int t = threadIdx.x;
  if (t < 192) qs[t] = qc[(size_t)r0*3 + t] * inv_p99[b];
  __syncthreads();
  const float w0 = W[t], w1 = W[DWID + t], w2 = W[2*DWID + t];
  const float bv = bias[t];
  float s = 0.f, q = 0.f;
  for (int m = 0; m < 64; ++m) {
    const float v = bv + qs[m*3]*w0 + qs[m*3+1]*w1 + qs[m*3+2]*w2;
    net[(size_t)(r0 + m)*DWID + t] = v;
    s += v; q += v*v;
  }
  part[blk*512 + t] = s;
  part[blk*512 + 256 + t] = q;
}

// ================= stat finalize (single block, 256 partials) =================
__global__ __launch_bounds__(1024) void k_statf(
    const float* __restrict__ part, float* __restrict__ stats)
{
  __shared__ float red[8][512];
  const int t = threadIdx.x;
  const int pbg = t >> 7;
  const int idx = (t & 127) * 4;
  f32x4 a = {};
  for (int pb = pbg; pb < 256; pb += 8)
    a = a + *reinterpret_cast<const f32x4*>(&part[pb*512 + idx]);
  *reinterpret_cast<f32x4*>(&red[pbg][idx]) = a;
  __syncthreads();
  if (t < 512) {
    float s = 0.f;
    #pragma unroll
    for (int g = 0; g < 8; ++g) s += red[g][t];
    red[0][t] = s;
  }
  __syncthreads();
  if (t < 256) {
    const float mean = red[0][t] * (1.f/16384.f);
    const float var  = red[0][256 + t] * (1.f/16384.f) - mean*mean;
    stats[t] = mean;
    stats[256 + t] = rsqrtf(var + 1e-5f);
  }
}

// ================= CBN + relu + MFMA matmul (+residual) + stat partials ======
__global__ __launch_bounds__(256) void k_cbnmm(
    const float* __restrict__ X, const float* __restrict__ stats,
    const float* __restrict__ gb, int gslot, int bslot,
    const __hip_bfloat16* __restrict__ wt,   // [256 n][256 k] bf16
    const float* __restrict__ bias,
    float* __restrict__ out, int addmode, float* __restrict__ part)
{
  __shared__ __align__(16) __hip_bfloat16 xs[64 * 256];  // swizzled [row][k]
  __shared__ float sred[4][2][128];
  const int t = threadIdx.x;
  const int blk = blockIdx.x;
  const int r0 = blk * 64;
  const int bb = r0 >> 11;

  // ---- stage: CBN + relu + bf16, XOR-swizzled on 16B groups ----
  {
    const int cq = (t & 63) * 4;
    const f32x4 mn = *reinterpret_cast<const f32x4*>(&stats[cq]);
    const f32x4 rs = *reinterpret_cast<const f32x4*>(&stats[256 + cq]);
    const f32x4 g  = *reinterpret_cast<const f32x4*>(&gb[((size_t)gslot*8 + bb)*DWID + cq]);
    const f32x4 be = *reinterpret_cast<const f32x4*>(&gb[((size_t)bslot*8 + bb)*DWID + cq]);
    const int rbase = t >> 6;
    #pragma unroll
    for (int j = 0; j < 16; ++j) {
      const int r = rbase + j*4;
      const f32x4 v = *reinterpret_cast<const f32x4*>(&X[(size_t)(r0 + r)*DWID + cq]);
      bf16x4 h;
      #pragma unroll
      for (int jj = 0; jj < 4; ++jj)
        h[jj] = (__bf16)fmaxf(0.f, (v[jj] - mn[jj])*rs[jj]*g[jj] + be[jj]);
      const int grp = (cq >> 3) ^ (r & 7);
      *reinterpret_cast<bf16x4*>((char*)xs + r*512 + grp*16 + (cq & 7)*2) = h;
    }
  }
  __syncthreads();

  const int lane = t & 63, wid = t >> 6;
  const int wm = wid >> 1, wn = wid & 1;
  f32x4 acc[2][8] = {};
  #pragma unroll
  for (int kstep = 0; kstep < 8; ++kstep) {
    const int ke = kstep*32 + (lane >> 4)*8;
    bf16x8 a[2], bfr[8];
    #pragma unroll
    for (int fm = 0; fm < 2; ++fm) {
      const int row = wm*32 + fm*16 + (lane & 15);
      a[fm] = *reinterpret_cast<const bf16x8*>(
          (char*)xs + row*512 + (((ke >> 3) ^ (row & 7))*16));
    }
    #pragma unroll
    for (int fn = 0; fn < 8; ++fn) {
      const int n = wn*128 + fn*16 + (lane & 15);
      bfr[fn] = *reinterpret_cast<const bf16x8*>(&wt[(size_t)n*DWID + ke]);
    }
    #pragma unroll
    for (int fm = 0; fm < 2; ++fm)
      #pragma unroll
      for (int fn = 0; fn < 8; ++fn)
        acc[fm][fn] = __builtin_amdgcn_mfma_f32_16x16x32_bf16(a[fm], bfr[fn], acc[fm][fn], 0, 0, 0);
  }

  // ---- epilogue: bias + residual + store + per-block column sums ----
  const int rb = (lane >> 4) * 4;
  #pragma unroll
  for (int fn = 0; fn < 8; ++fn) {
    const int gn = wn*128 + fn*16 + (lane & 15);
    const float bv = bias[gn];
    float s = 0.f, q = 0.f;
    #pragma unroll
    for (int fm = 0; fm < 2; ++fm) {
      const size_t row0 = (size_t)r0 + wm*32 + fm*16 + rb;
      #pragma unroll
      for (int r = 0; r < 4; ++r) {
        float v = acc[fm][fn][r] + bv;
        if (addmode) v += out[(row0 + r)*DWID + gn];
        out[(row0 + r)*DWID + gn] = v;
        s += v; q += v*v;
      }
    }
    s += __shfl_xor(s, 16); s += __shfl_xor(s, 32);
    q += __shfl_xor(q, 16); q += __shfl_xor(q, 32);
    if ((lane >> 4) == 0) {
      sred[wid][0][fn*16 + (lane & 15)] = s;
      sred[wid][1][fn*16 + (lane & 15)] = q;
    }
  }
  __syncthreads();
  {
    const int col = t;           // 0..255
    const int wn2 = col >> 7, cl = col & 127;
    const float s = sred[wn2][0][cl] + sred[2 + wn2][0][cl];
    const float q = sred[wn2][1][cl] + sred[2 + wn2][1][cl];
    part[blk*512 + col] = s;
    part[blk*512 + 256 + col] = q;
  }
}

// ================= final CBN + relu + fc_out =================
__global__ __launch_bounds__(256) void k_final(
    const float* __restrict__ net, const float* __restrict__ stats,
    const float* __restrict__ gb, const float* __restrict__ fcW,
    const float* __restrict__ fcb, float* __restrict__ out)
{
  const int wid = threadIdx.x >> 6, lane = threadIdx.x & 63;
  const int m = blockIdx.x*4 + wid;
  const int b = m >> 11;
  const int f0 = lane*4;
  const f32x4 x  = *reinterpret_cast<const f32x4*>(&net[(size_t)m*DWID + f0]);
  const f32x4 mn = *reinterpret_cast<const f32x4*>(&stats[f0]);
  const f32x4 rs = *reinterpret_cast<const f32x4*>(&stats[256 + f0]);
  const f32x4 g  = *reinterpret_cast<const f32x4*>(&gb[(20*8 + (size_t)b)*DWID + f0]);
  const f32x4 be = *reinterpret_cast<const f32x4*>(&gb[(21*8 + (size_t)b)*DWID + f0]);
  const f32x4 w  = *reinterpret_cast<const f32x4*>(&fcW[f0]);
  float s = 0.f;
  #pragma unroll
  for (int j = 0; j < 4; ++j)
    s += fmaxf(0.f, (x[j] - mn[j])*rs[j]*g[j] + be[j]) * w[j];
  #pragma unroll
  for (int o = 32; o > 0; o >>= 1) s += __shfl_down(s, o);
  if (lane == 0) out[m] = s + fcb[0];
}

// ================= launch =================
extern "C" void kernel_launch(void* const* d_in, const int* in_sizes, int n_in,
                              void* d_out, int out_size, void* d_ws, size_t ws_size,
                              hipStream_t stream) {
  (void)in_sizes; (void)n_in; (void)out_size;
  if (ws_size < WS_NEEDED) return;

  const float* pts    = (const float*)d_in[0];
  const float* rgb    = (const float*)d_in[1];
  const float* qc     = (const float*)d_in[2];
  const float* enc_W1 = (const float*)d_in[3];
  const float* enc_b1 = (const float*)d_in[4];
  const float* enc_W2 = (const float*)d_in[5];
  const float* enc_b2 = (const float*)d_in[6];
  const float* fc_p_W = (const float*)d_in[7];
  const float* fc_p_b = (const float*)d_in[8];
  const float* Wg0 = (const float*)d_in[9];
  const float* bg0 = (const float*)d_in[10];
  const float* Wb0 = (const float*)d_in[11];
  const float* bb0 = (const float*)d_in[12];
  const float* W0  = (const float*)d_in[13];
  const float* b0  = (const float*)d_in[14];
  const float* Wg1 = (const float*)d_in[15];
  const float* bg1 = (const float*)d_in[16];
  const float* Wb1 = (const float*)d_in[17];
  const float* bb1 = (const float*)d_in[18];
  const float* W1  = (const float*)d_in[19];
  const float* b1  = (const float*)d_in[20];
  const float* bnWg = (const float*)d_in[21];
  const float* bnbg = (const float*)d_in[22];
  const float* bnWb = (const float*)d_in[23];
  const float* bnbb = (const float*)d_in[24];
  const float* fcoW = (const float*)d_in[25];
  const float* fcob = (const float*)d_in[26];
  float* out = (float*)d_out;

  char* ws = (char*)d_ws;
  float* inv_p99 = (float*)(ws + OFF_INV);
  unsigned char* mask = (unsigned char*)(ws + OFF_MASK);
  float* c     = (float*)(ws + OFF_C);
  float* gbuf  = (float*)(ws + OFF_GB);
  float* stats = (float*)(ws + OFF_STATS);
  __hip_bfloat16* w2t = (__hip_bfloat16*)(ws + OFF_W2T);
  __hip_bfloat16* h1  = (__hip_bfloat16*)(ws + OFF_H1);
  __hip_bfloat16* wt  = (__hip_bfloat16*)(ws + OFF_WT);
  float* gbp  = (float*)(ws + OFF_GBP);
  float* part = (float*)(ws + OFF_PART);
  float* net = (float*)(ws + OFF_NET);
  float* dx  = (float*)(ws + OFF_DX);

  k_p99<<<NB, 1024, 0, stream>>>(pts, inv_p99, mask, c);
  k_w2t<<<dim3(16,16), 256, 0, stream>>>(enc_W2, w2t);
  for (int b = 0; b < NB; ++b) {
    k_enc1<<<NPTS/8, 256, 0, stream>>>(pts, rgb, inv_p99, enc_W1, enc_b1, h1, b);
    k_enc2<<<dim3(NPTS/EBM, CWID/EBN), 256, 0, stream>>>(h1, w2t, enc_b2,
                                                         mask + b*NPTS, c + b*CWID);
  }
  // h1 dead from here; wt/gbp/part alias its storage
  k_wt<<<dim3(4,4,10), 256, 0, stream>>>(W0, W1, wt);
  k_gbp<<<dim3(16,22), 256, 0, stream>>>(c, Wg0, Wb0, Wg1, Wb1, bnWg, bnWb, gbp);
  k_gbf<<<22, 256, 0, stream>>>(gbp, bg0, bb0, bg1, bb1, bnbg, bnbb, gbuf);

  k_fcp2<<<256, 256, 0, stream>>>(qc, inv_p99, fc_p_W, fc_p_b, net, part);
  k_statf<<<1, 1024, 0, stream>>>(part, stats);
  for (int i = 0; i < 5; ++i) {
    k_cbnmm<<<256, 256, 0, stream>>>(net, stats, gbuf, i, 5+i,
                                     wt + (size_t)i*DWID*DWID, b0 + i*DWID, dx, 0, part);
    k_statf<<<1, 1024, 0, stream>>>(part, stats);
    k_cbnmm<<<256, 256, 0, stream>>>(dx, stats, gbuf, 10+i, 15+i,
                                     wt + (size_t)(5+i)*DWID*DWID, b1 + i*DWID, net, 1, part);
    k_statf<<<1, 1024, 0, stream>>>(part, stats);
  }
  k_final<<<NB*NT/4, 256, 0, stream>>>(net, stats, gbuf, fcoW, fcob, out);
}